// Round 10
// baseline (383.928 us; speedup 1.0000x reference)
//
#include <hip/hip_runtime.h>
#include <hip/hip_bf16.h>

// RGCN: N=100000, F=128, R=4, E=1600000, L=2.
// R19: R18's diagnostic revealed scatter_cast_prep = ~50us (biggest single
// dispatch; VALUBusy 4.6%, VGPR_Count 16 -> per-edge register cache was in
// SCRATCH, + 782-way global-atomic contention on binCursor lines).
//  - scatter rewritten: no register edge cache (re-read edges in pass 2,
//    L2-hot at 2.4MB/XCD); EPB 2048->8192 (196 blocks: 4x less reservation
//    contention, ~21-entry contiguous chunks per bin for write coalescing).
//  - aggregate split reverted (the 2 extra dispatches cost a measured
//    ~11us); back to one full-grid dispatch per layer.
// Frozen: aggregate inner loop (fabric-floor, R12-R16: 70.5us, FETCH pinned
// at the 182MB 8-XCD distinct-row floor), 10-stage transform (<35us,
// proven R18), bin_fill (<35us, proven R18).
// R14 lesson: no instructions unverified on gfx950.
// R10 lesson: gather stays split from MFMA.
#define N_NODES 100000
#define FDIM 128
#define RREL 4
#define NEDGE 1600000
#define NSEG (N_NODES * RREL)          // 400000
#define KB_TOT 20                      // 640 / 32 k-steps
#define NSTAGE 10                      // 2 k-blocks per staged barrier
#define BSW_PER_LAYER (KB_TOT * 8 * 64 * 8) // 81920 bf16 elems = 160 KB
#define BIN_SHIFT 10                   // 1024 segs per bin
#define BIN_SEGS 1024
#define NBINS ((NSEG + BIN_SEGS - 1) / BIN_SEGS) // 391
#define BIN_CAP 5120                   // slab capacity (avg 4096, +16 sigma)
#define EPB 8192                       // edges per scatter block
#define SCAT_NB ((NEDGE + EPB - 1) / EPB)       // 196
#define CAST_NB ((N_NODES * FDIM / 4) / 256)    // 12500
#define PREP_NB (2 * BSW_PER_LAYER / 256)       // 640
#define CUR_BITS 21                    // cursor in [0, NBINS*BIN_CAP) < 2^21

typedef __attribute__((ext_vector_type(8))) short bfrag; // 8 bf16 (4 VGPR)
typedef __attribute__((ext_vector_type(4))) float ffrag; // 4 f32 acc
typedef __attribute__((ext_vector_type(2))) float f32x2; // packed f32 pair

__device__ __forceinline__ unsigned short f2bf(float f) {
    unsigned u = __float_as_uint(f);
    u += 0x7fffu + ((u >> 16) & 1u); // RNE
    return (unsigned short)(u >> 16);
}
__device__ __forceinline__ float bf_lo(unsigned u) { return __uint_as_float(u << 16); }
__device__ __forceinline__ float bf_hi(unsigned u) { return __uint_as_float(u & 0xffff0000u); }

// ---------- scatter_cast_prep: bin scatter + x cast + weight swizzle ----
// blocks [0, SCAT_NB): two-pass edge scatter (histogram; reserve; re-read
//   and place). No per-edge register cache -> no scratch traffic.
// blocks [SCAT_NB, +CAST_NB): x f32 -> bf16 cast
// blocks [SCAT_NB+CAST_NB, +PREP_NB): weight swizzle into MFMA B order
__global__ __launch_bounds__(256) void scatter_cast_prep(
    const int* __restrict__ src, const int* __restrict__ dst,
    const int* __restrict__ et, int* __restrict__ binCursor,
    unsigned* __restrict__ pairs,
    const float* __restrict__ x, unsigned short* __restrict__ xb,
    const float* __restrict__ W,    // [L,4,128,128]
    const float* __restrict__ root, // [L,128,128]
    unsigned short* __restrict__ Bsw)
{
    int tid = threadIdx.x;
    if (blockIdx.x >= SCAT_NB) {
        int t = blockIdx.x - SCAT_NB;
        if (t < CAST_NB) {
            int i = t * 256 + tid;
            float4 v = ((const float4*)x)[i];
            ushort4 o = { f2bf(v.x), f2bf(v.y), f2bf(v.z), f2bf(v.w) };
            ((ushort4*)xb)[i] = o;
        } else {
            int idx = (t - CAST_NB) * 256 + tid;
            int layer = idx / BSW_PER_LAYER;
            int rem = idx % BSW_PER_LAYER;
            int kb = rem / 4096;
            int rem2 = rem % 4096;
            int ct = rem2 / 512;
            int rem3 = rem2 % 512;
            int lane = rem3 / 8;
            int j = rem3 % 8;
            int k = kb * 32 + (lane >> 4) * 8 + j;
            int n = ct * 16 + (lane & 15);
            float v;
            if (k < 512) v = W[(size_t)layer * 4 * 128 * 128 + (size_t)k * 128 + n];
            else         v = root[(size_t)layer * 128 * 128 + (size_t)(k - 512) * 128 + n];
            Bsw[idx] = f2bf(v);
        }
        return;
    }
    __shared__ int hist[NBINS];
    __shared__ int base[NBINS];
    for (int b = tid; b < NBINS; b += 256) hist[b] = 0;
    __syncthreads();
    int e0 = blockIdx.x * EPB;
    int eEnd = min(e0 + EPB, NEDGE);
    // pass 1: histogram by bin
    for (int e = e0 + tid; e < eEnd; e += 256)
        atomicAdd(&hist[(dst[e] * RREL + et[e]) >> BIN_SHIFT], 1);
    __syncthreads();
    // reserve one contiguous chunk per non-empty bin
    for (int b = tid; b < NBINS; b += 256) {
        int h = hist[b];
        base[b] = h ? atomicAdd(&binCursor[b], h) : 0;
        hist[b] = 0; // reuse as local arrival cursor
    }
    __syncthreads();
    // pass 2: re-read edges (L2-hot) and place packed (src<<10 | segLocal)
    for (int e = e0 + tid; e < eEnd; e += 256) {
        int seg = dst[e] * RREL + et[e];
        int b = seg >> BIN_SHIFT;
        int li = atomicAdd(&hist[b], 1);
        pairs[(size_t)b * BIN_CAP + base[b] + li] =
            ((unsigned)src[e] << BIN_SHIFT) | (unsigned)(seg & (BIN_SEGS - 1));
    }
}

// ---------- bin pass 2: local hist+scan, emit packed cursor, place esrc ----
__global__ __launch_bounds__(1024) void bin_fill(
    const unsigned* __restrict__ pairs, const int* __restrict__ binCursor,
    int* __restrict__ esrc, unsigned* __restrict__ cursorp)
{
    __shared__ int hist[BIN_SEGS];
    __shared__ int cur[BIN_SEGS];
    __shared__ int waveSums[16];
    int b = blockIdx.x;
    int tid = threadIdx.x;
    int seg0 = b << BIN_SHIFT;
    int cnt = binCursor[b];
    size_t pb = (size_t)b * BIN_CAP;
    hist[tid] = 0;
    __syncthreads();
    for (int i = tid; i < cnt; i += 1024)
        atomicAdd(&hist[pairs[pb + i] & (BIN_SEGS - 1)], 1);
    __syncthreads();
    // exclusive scan of hist[0..1023]
    int v = hist[tid];
    int lane = tid & 63, wv = tid >> 6;
    int inc = v;
    #pragma unroll
    for (int d = 1; d < 64; d <<= 1) {
        int o = __shfl_up(inc, d, 64);
        if (lane >= d) inc += o;
    }
    if (lane == 63) waveSums[wv] = inc;
    __syncthreads();
    int wbase = 0;
    for (int w = 0; w < wv; ++w) wbase += waveSums[w];
    int glob = (int)pb + wbase + inc - v; // global esrc start for this segment
    int sg = seg0 + tid;
    if (sg < NSEG) cursorp[sg] = (unsigned)glob | ((unsigned)v << CUR_BITS);
    cur[tid] = glob;
    __syncthreads();
    for (int i = tid; i < cnt; i += 1024) {
        unsigned p = pairs[pb + i];
        int pos = atomicAdd(&cur[p & (BIN_SEGS - 1)], 1);
        esrc[pos] = (int)(p >> BIN_SHIFT);
    }
}

// ---------- per-segment gather-reduce, 16 lanes/segment (frozen) ----------
__device__ __forceinline__ uint4 ldrow(const unsigned short* xb, int s, int lane16) {
    unsigned off = (unsigned)s * (FDIM * 2) + (unsigned)lane16 * 16u;
    return *(const uint4*)((const char*)xb + off);
}
__device__ __forceinline__ void acc_add(f32x2* acc, uint4 u) {
    f32x2 t0 = {bf_lo(u.x), bf_hi(u.x)}; acc[0] += t0;
    f32x2 t1 = {bf_lo(u.y), bf_hi(u.y)}; acc[1] += t1;
    f32x2 t2 = {bf_lo(u.z), bf_hi(u.z)}; acc[2] += t2;
    f32x2 t3 = {bf_lo(u.w), bf_hi(u.w)}; acc[3] += t3;
}

__global__ __launch_bounds__(256) void rgcn_aggregate(
    const unsigned short* __restrict__ xb, const int* __restrict__ esrc,
    const unsigned* __restrict__ cursorp,
    unsigned short* __restrict__ meanb)
{
    int sub = threadIdx.x >> 4;
    int lane16 = threadIdx.x & 15;
    int seg = blockIdx.x * 16 + sub;
    unsigned cc = cursorp[seg];
    int j = (int)(cc & ((1u << CUR_BITS) - 1u));
    int c = (int)(cc >> CUR_BITS);
    int end = j + c;
    f32x2 acc[4] = {};
    for (; j + 3 < end; j += 4) {
        int s0 = esrc[j], s1 = esrc[j + 1], s2 = esrc[j + 2], s3 = esrc[j + 3];
        uint4 u0 = ldrow(xb, s0, lane16);
        uint4 u1 = ldrow(xb, s1, lane16);
        uint4 u2 = ldrow(xb, s2, lane16);
        uint4 u3 = ldrow(xb, s3, lane16);
        acc_add(acc, u0); acc_add(acc, u1); acc_add(acc, u2); acc_add(acc, u3);
    }
    for (; j < end; ++j) {
        int sv = esrc[j];
        uint4 u = ldrow(xb, sv, lane16);
        acc_add(acc, u);
    }
    float inv = 1.0f / fmaxf((float)c, 1.0f);
    uint4 o;
    o.x = (unsigned)f2bf(acc[0].x * inv) | ((unsigned)f2bf(acc[0].y * inv) << 16);
    o.y = (unsigned)f2bf(acc[1].x * inv) | ((unsigned)f2bf(acc[1].y * inv) << 16);
    o.z = (unsigned)f2bf(acc[2].x * inv) | ((unsigned)f2bf(acc[2].y * inv) << 16);
    o.w = (unsigned)f2bf(acc[3].x * inv) | ((unsigned)f2bf(acc[3].y * inv) << 16);
    ((uint4*)(meanb + (size_t)seg * FDIM))[lane16] = o;
}

// ---------- MFMA transform: 10-stage (2 kb/stage) async-staged dbuf ------
__device__ __forceinline__ void gload_lds16(const void* g, void* l) {
    __builtin_amdgcn_global_load_lds(
        (const __attribute__((address_space(1))) unsigned*)g,
        (__attribute__((address_space(3))) unsigned*)l, 16, 0, 0);
}

__global__ __launch_bounds__(256, 3) void rgcn_transform(
    const unsigned short* __restrict__ xb,    // [N,128] bf16 activations
    const unsigned short* __restrict__ meanb, // [N,512] bf16
    const unsigned short* __restrict__ Bsw,   // this layer's [20][8][64][8]
    const float* __restrict__ bias,           // [128]
    float* __restrict__ out,                  // [N,128] f32 (live iff writeF32)
    unsigned short* __restrict__ xbn,         // [N,128] bf16 (live iff !writeF32)
    const int writeF32)
{
    __shared__ __align__(16) unsigned char Bsm[2][16384]; // 2 kb per stage

    int tid = threadIdx.x;
    int wave = tid >> 6, lane = tid & 63;
    int quad = lane >> 4, rlo = lane & 15;
    int n0 = blockIdx.x * 128 + wave * 32;
    int r0c = min(n0 + rlo, N_NODES - 1);
    int r1c = min(n0 + 16 + rlo, N_NODES - 1);

    const bfrag* m0 = (const bfrag*)(meanb + (size_t)r0c * 512) + quad;
    const bfrag* m1 = (const bfrag*)(meanb + (size_t)r1c * 512) + quad;
    const bfrag* x0 = (const bfrag*)(xb + (size_t)r0c * FDIM) + quad;
    const bfrag* x1 = (const bfrag*)(xb + (size_t)r1c * FDIM) + quad;

    const char* gBc = (const char*)Bsw;
    #define STAGE_B(st, buf) do { \
        const char* _g = gBc + (size_t)(st) * 16384 + tid * 16; \
        char* _l = (char*)Bsm[buf] + wave * 1024; \
        gload_lds16(_g, _l); \
        gload_lds16(_g + 4096, _l + 4096); \
        gload_lds16(_g + 8192, _l + 8192); \
        gload_lds16(_g + 12288, _l + 12288); \
    } while (0)

    #define AFRAG(row, kb) ((kb) < 16 ? row##_m[(kb) * 4] : row##_x[((kb) - 16) * 4])
    const bfrag* r0_m = m0; const bfrag* r0_x = x0;
    const bfrag* r1_m = m1; const bfrag* r1_x = x1;

    ffrag acc[2][8] = {};

    STAGE_B(0, 0);
    bfrag a00 = AFRAG(r0, 0), a10 = AFRAG(r1, 0); // kb even
    bfrag a01 = AFRAG(r0, 1), a11 = AFRAG(r1, 1); // kb odd
    __syncthreads();

    #pragma unroll
    for (int st = 0; st < NSTAGE; ++st) {
        int cur = st & 1;
        bfrag n00 = a00, n10 = a10, n01 = a01, n11 = a11;
        if (st + 1 < NSTAGE) {
            STAGE_B(st + 1, cur ^ 1);
            n00 = AFRAG(r0, 2 * st + 2); n10 = AFRAG(r1, 2 * st + 2);
            n01 = AFRAG(r0, 2 * st + 3); n11 = AFRAG(r1, 2 * st + 3);
        }
        #pragma unroll
        for (int ct = 0; ct < 8; ++ct) {
            bfrag b = *(const bfrag*)&Bsm[cur][ct * 1024 + lane * 16];
            acc[0][ct] = __builtin_amdgcn_mfma_f32_16x16x32_bf16(a00, b, acc[0][ct], 0, 0, 0);
            acc[1][ct] = __builtin_amdgcn_mfma_f32_16x16x32_bf16(a10, b, acc[1][ct], 0, 0, 0);
        }
        #pragma unroll
        for (int ct = 0; ct < 8; ++ct) {
            bfrag b = *(const bfrag*)&Bsm[cur][8192 + ct * 1024 + lane * 16];
            acc[0][ct] = __builtin_amdgcn_mfma_f32_16x16x32_bf16(a01, b, acc[0][ct], 0, 0, 0);
            acc[1][ct] = __builtin_amdgcn_mfma_f32_16x16x32_bf16(a11, b, acc[1][ct], 0, 0, 0);
        }
        a00 = n00; a10 = n10; a01 = n01; a11 = n11;
        __syncthreads();
    }
    #undef STAGE_B
    #undef AFRAG

    float bcol[8];
    #pragma unroll
    for (int ct = 0; ct < 8; ++ct) bcol[ct] = bias[ct * 16 + rlo];

    #pragma unroll
    for (int rt = 0; rt < 2; ++rt) {
        int rbase = n0 + rt * 16 + quad * 4;
        #pragma unroll
        for (int i = 0; i < 4; ++i) {
            int r = rbase + i;
            if (r < N_NODES) {
                #pragma unroll
                for (int ct = 0; ct < 8; ++ct) {
                    float v = fmaxf(acc[rt][ct][i] + bcol[ct], 0.0f);
                    int col = ct * 16 + rlo;
                    if (writeF32) out[(size_t)r * FDIM + col] = v;
                    else          xbn[(size_t)r * FDIM + col] = f2bf(v);
                }
            }
        }
    }
}

extern "C" void kernel_launch(void* const* d_in, const int* in_sizes, int n_in,
                              void* d_out, int out_size, void* d_ws, size_t ws_size,
                              hipStream_t stream) {
    const float* x        = (const float*)d_in[0];
    const int* edge_index = (const int*)d_in[1]; // [2,E]
    const int* edge_type  = (const int*)d_in[2]; // [E]
    const float* weights  = (const float*)d_in[3]; // [L,R,F,F]
    const float* roots    = (const float*)d_in[4]; // [L,F,F]
    const float* biases   = (const float*)d_in[5]; // [L,F]
    float* out = (float*)d_out;

    // workspace layout; pairs aliases meanb (dead until aggregate runs)
    unsigned short* meanb = (unsigned short*)d_ws;            // NSEG*128 bf16 = 102.4 MB
    unsigned* pairs = (unsigned*)d_ws;                        // NBINS*CAP u32 = 8 MB (alias)
    unsigned short* xb0   = meanb + (size_t)NSEG * FDIM;      // N*128 bf16
    unsigned short* xb1   = xb0 + (size_t)N_NODES * FDIM;     // N*128 bf16
    unsigned short* Bsw   = xb1 + (size_t)N_NODES * FDIM;     // 2*81920 bf16
    int* esrc   = (int*)(Bsw + 2 * BSW_PER_LAYER);            // NBINS*CAP ints = 8 MB
    unsigned* cursorp = (unsigned*)(esrc + (size_t)NBINS * BIN_CAP); // NSEG packed
    int* binCursor = (int*)(cursorp + NSEG);                  // NBINS

    const int* src = edge_index;
    const int* dst = edge_index + NEDGE;

    hipMemsetAsync(binCursor, 0, NBINS * sizeof(int), stream);
    scatter_cast_prep<<<SCAT_NB + CAST_NB + PREP_NB, 256, 0, stream>>>(
        src, dst, edge_type, binCursor, pairs, x, xb0, weights, roots, Bsw);
    bin_fill<<<NBINS, 1024, 0, stream>>>(pairs, binCursor, esrc, cursorp);

    const int tgrid = (N_NODES + 127) / 128; // 782

    // layer 1: bf16 sidecar only
    rgcn_aggregate<<<NSEG / 16, 256, 0, stream>>>(xb0, esrc, cursorp, meanb);
    rgcn_transform<<<tgrid, 256, 0, stream>>>(xb0, meanb, Bsw, biases, out, xb1, 0);
    // layer 2: f32 output only
    rgcn_aggregate<<<NSEG / 16, 256, 0, stream>>>(xb1, esrc, cursorp, meanb);
    rgcn_transform<<<tgrid, 256, 0, stream>>>(xb1, meanb, Bsw + BSW_PER_LAYER,
                                              biases + FDIM, out, xb0, 1);
}

// Round 11
// 383.469 us; speedup vs baseline: 1.0012x; 1.0012x over previous
//
#include <hip/hip_runtime.h>
#include <hip/hip_bf16.h>

// RGCN: N=100000, F=128, R=4, E=1600000, L=2.
// R20 = completion of the scatter bisection R17/R19 muddled:
//   R17: register-cache (scratch-spilled, VGPR=16) + 782 blocks = 50us
//   R19: no-cache two-pass + 196 blocks = worse (~60us, over-serialized)
//   R20: no-cache two-pass + 782 blocks (EPB 2048) -- isolates the scratch
//        variable at proven parallelism. Pass-2 re-reads the block's own
//        16KB dst/et slice (L1/L2-hot).
// Everything else byte-identical to R17/R19 shared config.
// Frozen: aggregate (fabric floor 70.5us, FETCH pinned at 182MB 8-XCD
// distinct-row floor, R12-R16), 10-stage transform, bin_fill.
// R14 lesson: no instructions unverified on gfx950.
// R10 lesson: gather stays split from MFMA.
#define N_NODES 100000
#define FDIM 128
#define RREL 4
#define NEDGE 1600000
#define NSEG (N_NODES * RREL)          // 400000
#define KB_TOT 20                      // 640 / 32 k-steps
#define NSTAGE 10                      // 2 k-blocks per staged barrier
#define BSW_PER_LAYER (KB_TOT * 8 * 64 * 8) // 81920 bf16 elems = 160 KB
#define BIN_SHIFT 10                   // 1024 segs per bin
#define BIN_SEGS 1024
#define NBINS ((NSEG + BIN_SEGS - 1) / BIN_SEGS) // 391
#define BIN_CAP 5120                   // slab capacity (avg 4096, +16 sigma)
#define EPB 2048                       // edges per scatter block
#define SCAT_NB ((NEDGE + EPB - 1) / EPB)       // 782
#define CAST_NB ((N_NODES * FDIM / 4) / 256)    // 12500
#define PREP_NB (2 * BSW_PER_LAYER / 256)       // 640
#define CUR_BITS 21                    // cursor in [0, NBINS*BIN_CAP) < 2^21

typedef __attribute__((ext_vector_type(8))) short bfrag; // 8 bf16 (4 VGPR)
typedef __attribute__((ext_vector_type(4))) float ffrag; // 4 f32 acc
typedef __attribute__((ext_vector_type(2))) float f32x2; // packed f32 pair

__device__ __forceinline__ unsigned short f2bf(float f) {
    unsigned u = __float_as_uint(f);
    u += 0x7fffu + ((u >> 16) & 1u); // RNE
    return (unsigned short)(u >> 16);
}
__device__ __forceinline__ float bf_lo(unsigned u) { return __uint_as_float(u << 16); }
__device__ __forceinline__ float bf_hi(unsigned u) { return __uint_as_float(u & 0xffff0000u); }

// ---------- scatter_cast_prep: bin scatter + x cast + weight swizzle ----
// blocks [0, SCAT_NB): two-pass edge scatter (histogram; reserve; re-read
//   and place). No per-edge register cache -> no scratch traffic.
// blocks [SCAT_NB, +CAST_NB): x f32 -> bf16 cast
// blocks [SCAT_NB+CAST_NB, +PREP_NB): weight swizzle into MFMA B order
__global__ __launch_bounds__(256) void scatter_cast_prep(
    const int* __restrict__ src, const int* __restrict__ dst,
    const int* __restrict__ et, int* __restrict__ binCursor,
    unsigned* __restrict__ pairs,
    const float* __restrict__ x, unsigned short* __restrict__ xb,
    const float* __restrict__ W,    // [L,4,128,128]
    const float* __restrict__ root, // [L,128,128]
    unsigned short* __restrict__ Bsw)
{
    int tid = threadIdx.x;
    if (blockIdx.x >= SCAT_NB) {
        int t = blockIdx.x - SCAT_NB;
        if (t < CAST_NB) {
            int i = t * 256 + tid;
            float4 v = ((const float4*)x)[i];
            ushort4 o = { f2bf(v.x), f2bf(v.y), f2bf(v.z), f2bf(v.w) };
            ((ushort4*)xb)[i] = o;
        } else {
            int idx = (t - CAST_NB) * 256 + tid;
            int layer = idx / BSW_PER_LAYER;
            int rem = idx % BSW_PER_LAYER;
            int kb = rem / 4096;
            int rem2 = rem % 4096;
            int ct = rem2 / 512;
            int rem3 = rem2 % 512;
            int lane = rem3 / 8;
            int j = rem3 % 8;
            int k = kb * 32 + (lane >> 4) * 8 + j;
            int n = ct * 16 + (lane & 15);
            float v;
            if (k < 512) v = W[(size_t)layer * 4 * 128 * 128 + (size_t)k * 128 + n];
            else         v = root[(size_t)layer * 128 * 128 + (size_t)(k - 512) * 128 + n];
            Bsw[idx] = f2bf(v);
        }
        return;
    }
    __shared__ int hist[NBINS];
    __shared__ int base[NBINS];
    for (int b = tid; b < NBINS; b += 256) hist[b] = 0;
    __syncthreads();
    int e0 = blockIdx.x * EPB;
    int eEnd = min(e0 + EPB, NEDGE);
    // pass 1: histogram by bin
    for (int e = e0 + tid; e < eEnd; e += 256)
        atomicAdd(&hist[(dst[e] * RREL + et[e]) >> BIN_SHIFT], 1);
    __syncthreads();
    // reserve one contiguous chunk per non-empty bin
    for (int b = tid; b < NBINS; b += 256) {
        int h = hist[b];
        base[b] = h ? atomicAdd(&binCursor[b], h) : 0;
        hist[b] = 0; // reuse as local arrival cursor
    }
    __syncthreads();
    // pass 2: re-read edges (L1/L2-hot 16KB slice) and place packed entry
    for (int e = e0 + tid; e < eEnd; e += 256) {
        int seg = dst[e] * RREL + et[e];
        int b = seg >> BIN_SHIFT;
        int li = atomicAdd(&hist[b], 1);
        pairs[(size_t)b * BIN_CAP + base[b] + li] =
            ((unsigned)src[e] << BIN_SHIFT) | (unsigned)(seg & (BIN_SEGS - 1));
    }
}

// ---------- bin pass 2: local hist+scan, emit packed cursor, place esrc ----
__global__ __launch_bounds__(1024) void bin_fill(
    const unsigned* __restrict__ pairs, const int* __restrict__ binCursor,
    int* __restrict__ esrc, unsigned* __restrict__ cursorp)
{
    __shared__ int hist[BIN_SEGS];
    __shared__ int cur[BIN_SEGS];
    __shared__ int waveSums[16];
    int b = blockIdx.x;
    int tid = threadIdx.x;
    int seg0 = b << BIN_SHIFT;
    int cnt = binCursor[b];
    size_t pb = (size_t)b * BIN_CAP;
    hist[tid] = 0;
    __syncthreads();
    for (int i = tid; i < cnt; i += 1024)
        atomicAdd(&hist[pairs[pb + i] & (BIN_SEGS - 1)], 1);
    __syncthreads();
    // exclusive scan of hist[0..1023]
    int v = hist[tid];
    int lane = tid & 63, wv = tid >> 6;
    int inc = v;
    #pragma unroll
    for (int d = 1; d < 64; d <<= 1) {
        int o = __shfl_up(inc, d, 64);
        if (lane >= d) inc += o;
    }
    if (lane == 63) waveSums[wv] = inc;
    __syncthreads();
    int wbase = 0;
    for (int w = 0; w < wv; ++w) wbase += waveSums[w];
    int glob = (int)pb + wbase + inc - v; // global esrc start for this segment
    int sg = seg0 + tid;
    if (sg < NSEG) cursorp[sg] = (unsigned)glob | ((unsigned)v << CUR_BITS);
    cur[tid] = glob;
    __syncthreads();
    for (int i = tid; i < cnt; i += 1024) {
        unsigned p = pairs[pb + i];
        int pos = atomicAdd(&cur[p & (BIN_SEGS - 1)], 1);
        esrc[pos] = (int)(p >> BIN_SHIFT);
    }
}

// ---------- per-segment gather-reduce, 16 lanes/segment (frozen) ----------
__device__ __forceinline__ uint4 ldrow(const unsigned short* xb, int s, int lane16) {
    unsigned off = (unsigned)s * (FDIM * 2) + (unsigned)lane16 * 16u;
    return *(const uint4*)((const char*)xb + off);
}
__device__ __forceinline__ void acc_add(f32x2* acc, uint4 u) {
    f32x2 t0 = {bf_lo(u.x), bf_hi(u.x)}; acc[0] += t0;
    f32x2 t1 = {bf_lo(u.y), bf_hi(u.y)}; acc[1] += t1;
    f32x2 t2 = {bf_lo(u.z), bf_hi(u.z)}; acc[2] += t2;
    f32x2 t3 = {bf_lo(u.w), bf_hi(u.w)}; acc[3] += t3;
}

__global__ __launch_bounds__(256) void rgcn_aggregate(
    const unsigned short* __restrict__ xb, const int* __restrict__ esrc,
    const unsigned* __restrict__ cursorp,
    unsigned short* __restrict__ meanb)
{
    int sub = threadIdx.x >> 4;
    int lane16 = threadIdx.x & 15;
    int seg = blockIdx.x * 16 + sub;
    unsigned cc = cursorp[seg];
    int j = (int)(cc & ((1u << CUR_BITS) - 1u));
    int c = (int)(cc >> CUR_BITS);
    int end = j + c;
    f32x2 acc[4] = {};
    for (; j + 3 < end; j += 4) {
        int s0 = esrc[j], s1 = esrc[j + 1], s2 = esrc[j + 2], s3 = esrc[j + 3];
        uint4 u0 = ldrow(xb, s0, lane16);
        uint4 u1 = ldrow(xb, s1, lane16);
        uint4 u2 = ldrow(xb, s2, lane16);
        uint4 u3 = ldrow(xb, s3, lane16);
        acc_add(acc, u0); acc_add(acc, u1); acc_add(acc, u2); acc_add(acc, u3);
    }
    for (; j < end; ++j) {
        int sv = esrc[j];
        uint4 u = ldrow(xb, sv, lane16);
        acc_add(acc, u);
    }
    float inv = 1.0f / fmaxf((float)c, 1.0f);
    uint4 o;
    o.x = (unsigned)f2bf(acc[0].x * inv) | ((unsigned)f2bf(acc[0].y * inv) << 16);
    o.y = (unsigned)f2bf(acc[1].x * inv) | ((unsigned)f2bf(acc[1].y * inv) << 16);
    o.z = (unsigned)f2bf(acc[2].x * inv) | ((unsigned)f2bf(acc[2].y * inv) << 16);
    o.w = (unsigned)f2bf(acc[3].x * inv) | ((unsigned)f2bf(acc[3].y * inv) << 16);
    ((uint4*)(meanb + (size_t)seg * FDIM))[lane16] = o;
}

// ---------- MFMA transform: 10-stage (2 kb/stage) async-staged dbuf ------
__device__ __forceinline__ void gload_lds16(const void* g, void* l) {
    __builtin_amdgcn_global_load_lds(
        (const __attribute__((address_space(1))) unsigned*)g,
        (__attribute__((address_space(3))) unsigned*)l, 16, 0, 0);
}

__global__ __launch_bounds__(256, 3) void rgcn_transform(
    const unsigned short* __restrict__ xb,    // [N,128] bf16 activations
    const unsigned short* __restrict__ meanb, // [N,512] bf16
    const unsigned short* __restrict__ Bsw,   // this layer's [20][8][64][8]
    const float* __restrict__ bias,           // [128]
    float* __restrict__ out,                  // [N,128] f32 (live iff writeF32)
    unsigned short* __restrict__ xbn,         // [N,128] bf16 (live iff !writeF32)
    const int writeF32)
{
    __shared__ __align__(16) unsigned char Bsm[2][16384]; // 2 kb per stage

    int tid = threadIdx.x;
    int wave = tid >> 6, lane = tid & 63;
    int quad = lane >> 4, rlo = lane & 15;
    int n0 = blockIdx.x * 128 + wave * 32;
    int r0c = min(n0 + rlo, N_NODES - 1);
    int r1c = min(n0 + 16 + rlo, N_NODES - 1);

    const bfrag* m0 = (const bfrag*)(meanb + (size_t)r0c * 512) + quad;
    const bfrag* m1 = (const bfrag*)(meanb + (size_t)r1c * 512) + quad;
    const bfrag* x0 = (const bfrag*)(xb + (size_t)r0c * FDIM) + quad;
    const bfrag* x1 = (const bfrag*)(xb + (size_t)r1c * FDIM) + quad;

    const char* gBc = (const char*)Bsw;
    #define STAGE_B(st, buf) do { \
        const char* _g = gBc + (size_t)(st) * 16384 + tid * 16; \
        char* _l = (char*)Bsm[buf] + wave * 1024; \
        gload_lds16(_g, _l); \
        gload_lds16(_g + 4096, _l + 4096); \
        gload_lds16(_g + 8192, _l + 8192); \
        gload_lds16(_g + 12288, _l + 12288); \
    } while (0)

    #define AFRAG(row, kb) ((kb) < 16 ? row##_m[(kb) * 4] : row##_x[((kb) - 16) * 4])
    const bfrag* r0_m = m0; const bfrag* r0_x = x0;
    const bfrag* r1_m = m1; const bfrag* r1_x = x1;

    ffrag acc[2][8] = {};

    STAGE_B(0, 0);
    bfrag a00 = AFRAG(r0, 0), a10 = AFRAG(r1, 0); // kb even
    bfrag a01 = AFRAG(r0, 1), a11 = AFRAG(r1, 1); // kb odd
    __syncthreads();

    #pragma unroll
    for (int st = 0; st < NSTAGE; ++st) {
        int cur = st & 1;
        bfrag n00 = a00, n10 = a10, n01 = a01, n11 = a11;
        if (st + 1 < NSTAGE) {
            STAGE_B(st + 1, cur ^ 1);
            n00 = AFRAG(r0, 2 * st + 2); n10 = AFRAG(r1, 2 * st + 2);
            n01 = AFRAG(r0, 2 * st + 3); n11 = AFRAG(r1, 2 * st + 3);
        }
        #pragma unroll
        for (int ct = 0; ct < 8; ++ct) {
            bfrag b = *(const bfrag*)&Bsm[cur][ct * 1024 + lane * 16];
            acc[0][ct] = __builtin_amdgcn_mfma_f32_16x16x32_bf16(a00, b, acc[0][ct], 0, 0, 0);
            acc[1][ct] = __builtin_amdgcn_mfma_f32_16x16x32_bf16(a10, b, acc[1][ct], 0, 0, 0);
        }
        #pragma unroll
        for (int ct = 0; ct < 8; ++ct) {
            bfrag b = *(const bfrag*)&Bsm[cur][8192 + ct * 1024 + lane * 16];
            acc[0][ct] = __builtin_amdgcn_mfma_f32_16x16x32_bf16(a01, b, acc[0][ct], 0, 0, 0);
            acc[1][ct] = __builtin_amdgcn_mfma_f32_16x16x32_bf16(a11, b, acc[1][ct], 0, 0, 0);
        }
        a00 = n00; a10 = n10; a01 = n01; a11 = n11;
        __syncthreads();
    }
    #undef STAGE_B
    #undef AFRAG

    float bcol[8];
    #pragma unroll
    for (int ct = 0; ct < 8; ++ct) bcol[ct] = bias[ct * 16 + rlo];

    #pragma unroll
    for (int rt = 0; rt < 2; ++rt) {
        int rbase = n0 + rt * 16 + quad * 4;
        #pragma unroll
        for (int i = 0; i < 4; ++i) {
            int r = rbase + i;
            if (r < N_NODES) {
                #pragma unroll
                for (int ct = 0; ct < 8; ++ct) {
                    float v = fmaxf(acc[rt][ct][i] + bcol[ct], 0.0f);
                    int col = ct * 16 + rlo;
                    if (writeF32) out[(size_t)r * FDIM + col] = v;
                    else          xbn[(size_t)r * FDIM + col] = f2bf(v);
                }
            }
        }
    }
}

extern "C" void kernel_launch(void* const* d_in, const int* in_sizes, int n_in,
                              void* d_out, int out_size, void* d_ws, size_t ws_size,
                              hipStream_t stream) {
    const float* x        = (const float*)d_in[0];
    const int* edge_index = (const int*)d_in[1]; // [2,E]
    const int* edge_type  = (const int*)d_in[2]; // [E]
    const float* weights  = (const float*)d_in[3]; // [L,R,F,F]
    const float* roots    = (const float*)d_in[4]; // [L,F,F]
    const float* biases   = (const float*)d_in[5]; // [L,F]
    float* out = (float*)d_out;

    // workspace layout; pairs aliases meanb (dead until aggregate runs)
    unsigned short* meanb = (unsigned short*)d_ws;            // NSEG*128 bf16 = 102.4 MB
    unsigned* pairs = (unsigned*)d_ws;                        // NBINS*CAP u32 = 8 MB (alias)
    unsigned short* xb0   = meanb + (size_t)NSEG * FDIM;      // N*128 bf16
    unsigned short* xb1   = xb0 + (size_t)N_NODES * FDIM;     // N*128 bf16
    unsigned short* Bsw   = xb1 + (size_t)N_NODES * FDIM;     // 2*81920 bf16
    int* esrc   = (int*)(Bsw + 2 * BSW_PER_LAYER);            // NBINS*CAP ints = 8 MB
    unsigned* cursorp = (unsigned*)(esrc + (size_t)NBINS * BIN_CAP); // NSEG packed
    int* binCursor = (int*)(cursorp + NSEG);                  // NBINS

    const int* src = edge_index;
    const int* dst = edge_index + NEDGE;

    hipMemsetAsync(binCursor, 0, NBINS * sizeof(int), stream);
    scatter_cast_prep<<<SCAT_NB + CAST_NB + PREP_NB, 256, 0, stream>>>(
        src, dst, edge_type, binCursor, pairs, x, xb0, weights, roots, Bsw);
    bin_fill<<<NBINS, 1024, 0, stream>>>(pairs, binCursor, esrc, cursorp);

    const int tgrid = (N_NODES + 127) / 128; // 782

    // layer 1: bf16 sidecar only
    rgcn_aggregate<<<NSEG / 16, 256, 0, stream>>>(xb0, esrc, cursorp, meanb);
    rgcn_transform<<<tgrid, 256, 0, stream>>>(xb0, meanb, Bsw, biases, out, xb1, 0);
    // layer 2: f32 output only
    rgcn_aggregate<<<NSEG / 16, 256, 0, stream>>>(xb1, esrc, cursorp, meanb);
    rgcn_transform<<<tgrid, 256, 0, stream>>>(xb1, meanb, Bsw + BSW_PER_LAYER,
                                              biases + FDIM, out, xb0, 1);
}

// Round 12
// 365.290 us; speedup vs baseline: 1.0510x; 1.0498x over previous
//
#include <hip/hip_runtime.h>
#include <hip/hip_bf16.h>

// RGCN: N=100000, F=128, R=4, E=1600000, L=2.
// R21 = restore of R16, the session's measured-best configuration (366.7us).
// Bisection history that justifies each frozen piece:
//  - aggregate: fabric-floor (R12-R16: FETCH pinned at 182MB = 8-XCD
//    distinct-row floor; time invariant under ILP/VALU micro-variants).
//  - scatter: register-cached single-read form (3-arm bisection R17/R19/R20:
//    cached+782blk=50us beats no-cache at 196 or 782 blocks by ~15us --
//    the scratch round-trip pipelines better than a dependent L2 re-read).
//  - transform: 20-stage 8KB async dbuf at (256,3) (R16; 10-stage R17 was
//    equal within noise; barrier count is NOT the transform's cost).
//  - gaps: ~5.75us/dispatch boundary measured via R18's split experiment;
//    merging via cooperative launch contraindicated by R10 (gather needs
//    ~70% occupancy; merged-kernel resource max would cap it at ~37%).
// R14 lesson: no instructions unverified on gfx950 (fdot2 broke numerics).
// R10 lesson: gather stays split from MFMA.
#define N_NODES 100000
#define FDIM 128
#define RREL 4
#define NEDGE 1600000
#define NSEG (N_NODES * RREL)          // 400000
#define KB_TOT 20                      // 640 / 32 k-steps
#define BSW_PER_LAYER (KB_TOT * 8 * 64 * 8) // 81920 bf16 elems = 160 KB
#define BIN_SHIFT 10                   // 1024 segs per bin
#define BIN_SEGS 1024
#define NBINS ((NSEG + BIN_SEGS - 1) / BIN_SEGS) // 391
#define BIN_CAP 5120                   // slab capacity (avg 4096, +16 sigma)
#define EPB 2048                       // edges per bin_scatter block
#define SCAT_NB ((NEDGE + EPB - 1) / EPB)       // 782
#define CAST_NB ((N_NODES * FDIM / 4) / 256)    // 12500
#define PREP_NB (2 * BSW_PER_LAYER / 256)       // 640
#define CUR_BITS 21                    // cursor in [0, NBINS*BIN_CAP) < 2^21

typedef __attribute__((ext_vector_type(8))) short bfrag; // 8 bf16 (4 VGPR)
typedef __attribute__((ext_vector_type(4))) float ffrag; // 4 f32 acc
typedef __attribute__((ext_vector_type(2))) float f32x2; // packed f32 pair

__device__ __forceinline__ unsigned short f2bf(float f) {
    unsigned u = __float_as_uint(f);
    u += 0x7fffu + ((u >> 16) & 1u); // RNE
    return (unsigned short)(u >> 16);
}
__device__ __forceinline__ float bf_lo(unsigned u) { return __uint_as_float(u << 16); }
__device__ __forceinline__ float bf_hi(unsigned u) { return __uint_as_float(u & 0xffff0000u); }

// ---------- prepA: swizzle weights + zero binCursor (tiny) ----------
__global__ __launch_bounds__(256) void prepA(
    const float* __restrict__ W,    // [L,4,128,128]
    const float* __restrict__ root, // [L,128,128]
    unsigned short* __restrict__ Bsw,
    int* __restrict__ binCursor)
{
    int wb = blockIdx.x;
    int idx = wb * 256 + threadIdx.x;
    if (wb < 2) {
        int t = wb * 256 + threadIdx.x;
        if (t < NBINS) binCursor[t] = 0;
    }
    int layer = idx / BSW_PER_LAYER;
    int rem = idx % BSW_PER_LAYER;
    int kb = rem / 4096;
    int rem2 = rem % 4096;
    int ct = rem2 / 512;
    int rem3 = rem2 % 512;
    int lane = rem3 / 8;
    int j = rem3 % 8;
    int k = kb * 32 + (lane >> 4) * 8 + j;
    int n = ct * 16 + (lane & 15);
    float v;
    if (k < 512) v = W[(size_t)layer * 4 * 128 * 128 + (size_t)k * 128 + n];
    else         v = root[(size_t)layer * 128 * 128 + (size_t)(k - 512) * 128 + n];
    Bsw[idx] = f2bf(v);
}

// ---------- scatter_cast: bin scatter (blocks 0..781) + x cast (rest) ----
// pairs entry: (src << 10) | (seg & 1023). Register-cached edge data
// (spills to contiguous scratch -- measured faster than L2 re-read, R20).
__global__ __launch_bounds__(256) void scatter_cast(
    const int* __restrict__ src, const int* __restrict__ dst,
    const int* __restrict__ et, int* __restrict__ binCursor,
    unsigned* __restrict__ pairs,
    const float* __restrict__ x, unsigned short* __restrict__ xb)
{
    int tid = threadIdx.x;
    if (blockIdx.x >= SCAT_NB) {
        int i = (blockIdx.x - SCAT_NB) * 256 + tid;
        float4 v = ((const float4*)x)[i];
        ushort4 o = { f2bf(v.x), f2bf(v.y), f2bf(v.z), f2bf(v.w) };
        ((ushort4*)xb)[i] = o;
        return;
    }
    __shared__ int hist[NBINS];
    __shared__ int base[NBINS];
    for (int b = tid; b < NBINS; b += 256) hist[b] = 0;
    __syncthreads();
    int e0 = blockIdx.x * EPB;
    int binr[EPB / 256];
    unsigned pkr[EPB / 256];
    #pragma unroll
    for (int i = 0; i < EPB / 256; ++i) {
        int e = e0 + i * 256 + tid;
        if (e < NEDGE) {
            int seg = dst[e] * RREL + et[e];
            binr[i] = seg >> BIN_SHIFT;
            pkr[i] = ((unsigned)src[e] << BIN_SHIFT) | (unsigned)(seg & (BIN_SEGS - 1));
            atomicAdd(&hist[binr[i]], 1);
        } else binr[i] = -1;
    }
    __syncthreads();
    for (int b = tid; b < NBINS; b += 256) {
        int h = hist[b];
        base[b] = h ? atomicAdd(&binCursor[b], h) : 0;
        hist[b] = 0; // reuse as local arrival cursor
    }
    __syncthreads();
    #pragma unroll
    for (int i = 0; i < EPB / 256; ++i) {
        if (binr[i] >= 0) {
            int b = binr[i];
            int li = atomicAdd(&hist[b], 1);
            pairs[(size_t)b * BIN_CAP + base[b] + li] = pkr[i];
        }
    }
}

// ---------- bin pass 2: local hist+scan, emit packed cursor, place esrc ----
__global__ __launch_bounds__(1024) void bin_fill(
    const unsigned* __restrict__ pairs, const int* __restrict__ binCursor,
    int* __restrict__ esrc, unsigned* __restrict__ cursorp)
{
    __shared__ int hist[BIN_SEGS];
    __shared__ int cur[BIN_SEGS];
    __shared__ int waveSums[16];
    int b = blockIdx.x;
    int tid = threadIdx.x;
    int seg0 = b << BIN_SHIFT;
    int cnt = binCursor[b];
    size_t pb = (size_t)b * BIN_CAP;
    hist[tid] = 0;
    __syncthreads();
    for (int i = tid; i < cnt; i += 1024)
        atomicAdd(&hist[pairs[pb + i] & (BIN_SEGS - 1)], 1);
    __syncthreads();
    // exclusive scan of hist[0..1023]
    int v = hist[tid];
    int lane = tid & 63, wv = tid >> 6;
    int inc = v;
    #pragma unroll
    for (int d = 1; d < 64; d <<= 1) {
        int o = __shfl_up(inc, d, 64);
        if (lane >= d) inc += o;
    }
    if (lane == 63) waveSums[wv] = inc;
    __syncthreads();
    int wbase = 0;
    for (int w = 0; w < wv; ++w) wbase += waveSums[w];
    int glob = (int)pb + wbase + inc - v; // global esrc start for this segment
    int sg = seg0 + tid;
    if (sg < NSEG) cursorp[sg] = (unsigned)glob | ((unsigned)v << CUR_BITS);
    cur[tid] = glob;
    __syncthreads();
    for (int i = tid; i < cnt; i += 1024) {
        unsigned p = pairs[pb + i];
        int pos = atomicAdd(&cur[p & (BIN_SEGS - 1)], 1);
        esrc[pos] = (int)(p >> BIN_SHIFT);
    }
}

// ---------- per-segment gather-reduce, 16 lanes/segment (frozen) ----------
__device__ __forceinline__ uint4 ldrow(const unsigned short* xb, int s, int lane16) {
    unsigned off = (unsigned)s * (FDIM * 2) + (unsigned)lane16 * 16u;
    return *(const uint4*)((const char*)xb + off);
}
__device__ __forceinline__ void acc_add(f32x2* acc, uint4 u) {
    f32x2 t0 = {bf_lo(u.x), bf_hi(u.x)}; acc[0] += t0;
    f32x2 t1 = {bf_lo(u.y), bf_hi(u.y)}; acc[1] += t1;
    f32x2 t2 = {bf_lo(u.z), bf_hi(u.z)}; acc[2] += t2;
    f32x2 t3 = {bf_lo(u.w), bf_hi(u.w)}; acc[3] += t3;
}

__global__ __launch_bounds__(256) void rgcn_aggregate(
    const unsigned short* __restrict__ xb, const int* __restrict__ esrc,
    const unsigned* __restrict__ cursorp,
    unsigned short* __restrict__ meanb)
{
    int sub = threadIdx.x >> 4;
    int lane16 = threadIdx.x & 15;
    int seg = blockIdx.x * 16 + sub;
    unsigned cc = cursorp[seg];
    int j = (int)(cc & ((1u << CUR_BITS) - 1u));
    int c = (int)(cc >> CUR_BITS);
    int end = j + c;
    f32x2 acc[4] = {};
    for (; j + 3 < end; j += 4) {
        int s0 = esrc[j], s1 = esrc[j + 1], s2 = esrc[j + 2], s3 = esrc[j + 3];
        uint4 u0 = ldrow(xb, s0, lane16);
        uint4 u1 = ldrow(xb, s1, lane16);
        uint4 u2 = ldrow(xb, s2, lane16);
        uint4 u3 = ldrow(xb, s3, lane16);
        acc_add(acc, u0); acc_add(acc, u1); acc_add(acc, u2); acc_add(acc, u3);
    }
    for (; j < end; ++j) {
        int sv = esrc[j];
        uint4 u = ldrow(xb, sv, lane16);
        acc_add(acc, u);
    }
    float inv = 1.0f / fmaxf((float)c, 1.0f);
    uint4 o;
    o.x = (unsigned)f2bf(acc[0].x * inv) | ((unsigned)f2bf(acc[0].y * inv) << 16);
    o.y = (unsigned)f2bf(acc[1].x * inv) | ((unsigned)f2bf(acc[1].y * inv) << 16);
    o.z = (unsigned)f2bf(acc[2].x * inv) | ((unsigned)f2bf(acc[2].y * inv) << 16);
    o.w = (unsigned)f2bf(acc[3].x * inv) | ((unsigned)f2bf(acc[3].y * inv) << 16);
    ((uint4*)(meanb + (size_t)seg * FDIM))[lane16] = o;
}

// ---------- MFMA transform: 20-stage LDS dbuf + async B staging (R16) ----
__device__ __forceinline__ void gload_lds16(const void* g, void* l) {
    __builtin_amdgcn_global_load_lds(
        (const __attribute__((address_space(1))) unsigned*)g,
        (__attribute__((address_space(3))) unsigned*)l, 16, 0, 0);
}

__global__ __launch_bounds__(256, 3) void rgcn_transform(
    const unsigned short* __restrict__ xb,    // [N,128] bf16 activations
    const unsigned short* __restrict__ meanb, // [N,512] bf16
    const unsigned short* __restrict__ Bsw,   // this layer's [20][8][64][8]
    const float* __restrict__ bias,           // [128]
    float* __restrict__ out,                  // [N,128] f32 (live iff writeF32)
    unsigned short* __restrict__ xbn,         // [N,128] bf16 (live iff !writeF32)
    const int writeF32)
{
    __shared__ __align__(16) unsigned char Bsm[2][8192];

    int tid = threadIdx.x;
    int wave = tid >> 6, lane = tid & 63;
    int quad = lane >> 4, rlo = lane & 15;
    int n0 = blockIdx.x * 128 + wave * 32;
    int r0 = n0 + rlo;
    int r1 = n0 + 16 + rlo;
    int r0c = min(r0, N_NODES - 1);
    int r1c = min(r1, N_NODES - 1);

    const bfrag* m0 = (const bfrag*)(meanb + (size_t)r0c * 512) + quad;
    const bfrag* m1 = (const bfrag*)(meanb + (size_t)r1c * 512) + quad;
    const bfrag* x0 = (const bfrag*)(xb + (size_t)r0c * FDIM) + quad;
    const bfrag* x1 = (const bfrag*)(xb + (size_t)r1c * FDIM) + quad;

    // async width-16 staging: LDS dest is wave-uniform base + lane*16,
    // global src per-lane -- exactly our linear layout.
    const char* gBc = (const char*)Bsw;
    #define STAGE_B(kb, buf) do { \
        const char* _g = gBc + (size_t)(kb) * 8192 + tid * 16; \
        char* _l = (char*)Bsm[buf] + wave * 1024; \
        gload_lds16(_g, _l); \
        gload_lds16(_g + 4096, _l + 4096); \
    } while (0)

    #define AFRAG(row, kb) ((kb) < 16 ? row##_m[(kb) * 4] : row##_x[((kb) - 16) * 4])
    const bfrag* r0_m = m0; const bfrag* r0_x = x0;
    const bfrag* r1_m = m1; const bfrag* r1_x = x1;

    ffrag acc[2][8] = {};

    STAGE_B(0, 0);
    bfrag a0p0 = AFRAG(r0, 0), a1p0 = AFRAG(r1, 0);
    bfrag a0p1 = AFRAG(r0, 1), a1p1 = AFRAG(r1, 1);
    __syncthreads();

    #pragma unroll
    for (int kb = 0; kb < KB_TOT; ++kb) {
        int cur = kb & 1;
        if (kb + 1 < KB_TOT) STAGE_B(kb + 1, cur ^ 1);

        bfrag a0 = cur ? a0p1 : a0p0;
        bfrag a1 = cur ? a1p1 : a1p0;
        if (kb + 2 < KB_TOT) {
            if (cur) { a0p1 = AFRAG(r0, kb + 2); a1p1 = AFRAG(r1, kb + 2); }
            else     { a0p0 = AFRAG(r0, kb + 2); a1p0 = AFRAG(r1, kb + 2); }
        }

        #pragma unroll
        for (int ct = 0; ct < 8; ++ct) {
            bfrag b = *(const bfrag*)&Bsm[cur][ct * 1024 + lane * 16];
            acc[0][ct] = __builtin_amdgcn_mfma_f32_16x16x32_bf16(a0, b, acc[0][ct], 0, 0, 0);
            acc[1][ct] = __builtin_amdgcn_mfma_f32_16x16x32_bf16(a1, b, acc[1][ct], 0, 0, 0);
        }
        __syncthreads();
    }
    #undef STAGE_B
    #undef AFRAG

    float bcol[8];
    #pragma unroll
    for (int ct = 0; ct < 8; ++ct) bcol[ct] = bias[ct * 16 + rlo];

    #pragma unroll
    for (int rt = 0; rt < 2; ++rt) {
        int rbase = n0 + rt * 16 + quad * 4;
        #pragma unroll
        for (int i = 0; i < 4; ++i) {
            int r = rbase + i;
            if (r < N_NODES) {
                #pragma unroll
                for (int ct = 0; ct < 8; ++ct) {
                    float v = fmaxf(acc[rt][ct][i] + bcol[ct], 0.0f);
                    int col = ct * 16 + rlo;
                    if (writeF32) out[(size_t)r * FDIM + col] = v;
                    else          xbn[(size_t)r * FDIM + col] = f2bf(v);
                }
            }
        }
    }
}

extern "C" void kernel_launch(void* const* d_in, const int* in_sizes, int n_in,
                              void* d_out, int out_size, void* d_ws, size_t ws_size,
                              hipStream_t stream) {
    const float* x        = (const float*)d_in[0];
    const int* edge_index = (const int*)d_in[1]; // [2,E]
    const int* edge_type  = (const int*)d_in[2]; // [E]
    const float* weights  = (const float*)d_in[3]; // [L,R,F,F]
    const float* roots    = (const float*)d_in[4]; // [L,F,F]
    const float* biases   = (const float*)d_in[5]; // [L,F]
    float* out = (float*)d_out;

    // workspace layout; pairs aliases meanb (dead until aggregate runs)
    unsigned short* meanb = (unsigned short*)d_ws;            // NSEG*128 bf16 = 102.4 MB
    unsigned* pairs = (unsigned*)d_ws;                        // NBINS*CAP u32 = 8 MB (alias)
    unsigned short* xb0   = meanb + (size_t)NSEG * FDIM;      // N*128 bf16
    unsigned short* xb1   = xb0 + (size_t)N_NODES * FDIM;     // N*128 bf16
    unsigned short* Bsw   = xb1 + (size_t)N_NODES * FDIM;     // 2*81920 bf16
    int* esrc   = (int*)(Bsw + 2 * BSW_PER_LAYER);            // NBINS*CAP ints = 8 MB
    unsigned* cursorp = (unsigned*)(esrc + (size_t)NBINS * BIN_CAP); // NSEG packed
    int* binCursor = (int*)(cursorp + NSEG);                  // NBINS

    const int* src = edge_index;
    const int* dst = edge_index + NEDGE;

    // tiny prep: weight swizzle + binCursor zero
    prepA<<<PREP_NB, 256, 0, stream>>>(weights, roots, Bsw, binCursor);
    // scatter + cast in one dispatch (scatter blocks first; cast overlaps)
    scatter_cast<<<SCAT_NB + CAST_NB, 256, 0, stream>>>(src, dst, edge_type,
                                                        binCursor, pairs, x, xb0);
    bin_fill<<<NBINS, 1024, 0, stream>>>(pairs, binCursor, esrc, cursorp);

    const int tgrid = (N_NODES + 127) / 128; // 782

    // layer 1: bf16 sidecar only
    rgcn_aggregate<<<NSEG / 16, 256, 0, stream>>>(xb0, esrc, cursorp, meanb);
    rgcn_transform<<<tgrid, 256, 0, stream>>>(xb0, meanb, Bsw, biases, out, xb1, 0);
    // layer 2: f32 output only
    rgcn_aggregate<<<NSEG / 16, 256, 0, stream>>>(xb1, esrc, cursorp, meanb);
    rgcn_transform<<<tgrid, 256, 0, stream>>>(xb1, meanb, Bsw + BSW_PER_LAYER,
                                              biases + FDIM, out, xb0, 1);
}